// Round 1
// baseline (753.738 us; speedup 1.0000x reference)
//
#include <hip/hip_runtime.h>
#include <cstdint>

// Problem constants (from reference):
//   x: [4, 4096, 4096] fp32 -> rows of 128 over [T=16384, N_BANKS=32, BANK=128]
//   scores = |x| + bias[bank][:]  (bias broadcast over tokens)
//   mask = top-16 per row (ties -> lowest index, per jax.lax.top_k)
//   out0 = x * mask (same layout as x); out1 = num_assigned_tokens (pass-through)
#define BANKSZ   128
#define N_BANKS  32
#define TOPK     16
#define N_TOKENS (4 * 4096)
#define N_ROWS   (N_TOKENS * N_BANKS)      // 524288
#define OUT0_SZ  (N_TOKENS * N_BANKS * BANKSZ)  // 67108864
#define NAT_SZ   4096

// One wave (64 lanes) per row; lane L holds elements 2L, 2L+1 (float2 load,
// fully coalesced: 512B per wave, 2KB per 256-thread block).
// Top-16 threshold found by wave-cooperative radix select on monotone uint keys.
__global__ __launch_bounds__(256) void balanced_topk_kernel(
    const float* __restrict__ x,
    const float* __restrict__ bias,
    const float* __restrict__ nat,
    float* __restrict__ out)
{
    const int wave = threadIdx.x >> 6;
    const int lane = threadIdx.x & 63;
    const int row  = blockIdx.x * 4 + wave;

    // Fold the tiny second-output copy into the first 16 blocks (no extra launch).
    if (blockIdx.x < (NAT_SZ / 256)) {
        const int i = blockIdx.x * 256 + threadIdx.x;
        out[(size_t)OUT0_SZ + i] = nat[i];
    }

    const int bank = row & (N_BANKS - 1);

    const float2 v  = ((const float2*)(x    + (size_t)row * BANKSZ))[lane];
    const float2 bv = ((const float2*)(bias + (size_t)bank * BANKSZ))[lane];

    const float s0 = fabsf(v.x) + bv.x;
    const float s1 = fabsf(v.y) + bv.y;

    // Monotone float->uint mapping (handles negative scores for general bias).
    const uint32_t u0 = __float_as_uint(s0);
    const uint32_t u1 = __float_as_uint(s1);
    const uint32_t k0 = (u0 & 0x80000000u) ? ~u0 : (u0 | 0x80000000u);
    const uint32_t k1 = (u1 & 0x80000000u) ? ~u1 : (u1 | 0x80000000u);

    // Radix select, MSB -> LSB. Invariants:
    //   sel* : definitely in top-16
    //   act* : still a candidate
    //   need : top slots still to fill from candidates; cnt = |candidates|
    bool act0 = true,  act1 = true;
    bool sel0 = false, sel1 = false;
    int  need = TOPK;
    int  cnt  = 2 * 64;

    for (int b = 31; b >= 0; --b) {
        const uint32_t bit = 1u << b;
        const bool c0 = act0 && (k0 & bit);
        const bool c1 = act1 && (k1 & bit);
        const unsigned long long m0 = __ballot(c0);
        const unsigned long long m1 = __ballot(c1);
        const int c = __popcll(m0) + __popcll(m1);

        if (c == need) {            // bit=1 candidates exactly fill the top-k
            sel0 |= c0; sel1 |= c1;
            need = 0;
            break;
        }
        if (c > need) {             // threshold has this bit set; narrow to bit=1
            act0 = c0; act1 = c1; cnt = c;
        } else {                    // all bit=1 candidates are in; recurse on bit=0
            sel0 |= c0; sel1 |= c1;
            need -= c; cnt -= c;
            act0 = act0 && !(k0 & bit);
            act1 = act1 && !(k1 & bit);
            if (cnt == need) {      // remaining candidates exactly fill the top-k
                sel0 |= act0; sel1 |= act1;
                need = 0;
                break;
            }
        }
    }

    if (need > 0) {
        // All remaining candidates share an identical key (all 32 bits matched).
        // jax.lax.top_k tie-break: lowest index wins. Element index = 2*lane+slot.
        const unsigned long long m0 = __ballot(act0);
        const unsigned long long m1 = __ballot(act1);
        const unsigned long long lt = (1ULL << lane) - 1ULL;
        const int r0 = __popcll(m0 & lt) + __popcll(m1 & lt);
        const int r1 = r0 + (act0 ? 1 : 0);
        sel0 = sel0 || (act0 && (r0 < need));
        sel1 = sel1 || (act1 && (r1 < need));
    }

    float2 o;
    o.x = sel0 ? v.x : 0.0f;
    o.y = sel1 ? v.y : 0.0f;
    ((float2*)(out + (size_t)row * BANKSZ))[lane] = o;
}

extern "C" void kernel_launch(void* const* d_in, const int* in_sizes, int n_in,
                              void* d_out, int out_size, void* d_ws, size_t ws_size,
                              hipStream_t stream) {
    const float* x    = (const float*)d_in[0];
    const float* bias = (const float*)d_in[1];
    const float* nat  = (const float*)d_in[2];
    float* out = (float*)d_out;

    // 4 rows per 256-thread block (one wave64 per row).
    const int blocks = N_ROWS / 4;  // 131072
    balanced_topk_kernel<<<dim3(blocks), dim3(256), 0, stream>>>(x, bias, nat, out);
}

// Round 2
// 478.860 us; speedup vs baseline: 1.5740x; 1.5740x over previous
//
#include <hip/hip_runtime.h>
#include <cstdint>

// x: [4,4096,4096] fp32 -> rows of 128 over [T=16384, N_BANKS=32, BANK=128]
// scores = |x| + bias[bank][:]; mask = top-16 per row (ties -> lowest index);
// out0 = x * mask; out1 = num_assigned_tokens (pass-through).
#define BANKSZ   128
#define N_BANKS  32
#define TOPK     16
#define N_TOKENS (4 * 4096)
#define N_ROWS   (N_TOKENS * N_BANKS)           // 524288
#define OUT0_SZ  (N_TOKENS * N_BANKS * BANKSZ)  // 67108864
#define NAT_SZ   4096

// One wave per row, lane L holds elements 2L, 2L+1.
// Threshold T = 16th-largest monotone key, found by wave-uniform binary search
// on the key value: only state is the bracket [LO,HI) — no per-lane masks,
// so every round is 2 VALU (v_cmp ballots) + a handful of SALU.
// Rounds 1-2 are seeded at the expected quantile of the 16th-of-128 order
// statistic for |N(0,1)| data (~1.53 +/- 0.12); seeding is exact for ANY data
// because c_ge is monotone (a probe can only tighten a valid bracket).
__global__ __launch_bounds__(256) void balanced_topk_kernel(
    const float* __restrict__ x,
    const float* __restrict__ bias,
    const float* __restrict__ nat,
    float* __restrict__ out)
{
    const int wave = threadIdx.x >> 6;
    const int lane = threadIdx.x & 63;
    const int row  = blockIdx.x * 4 + wave;

    // Fold the tiny second-output copy into the first 16 blocks.
    if (blockIdx.x < (NAT_SZ / 256)) {
        const int i = blockIdx.x * 256 + threadIdx.x;
        out[(size_t)OUT0_SZ + i] = nat[i];
    }

    const int bank = row & (N_BANKS - 1);

    const float2 v  = ((const float2*)(x    + (size_t)row * BANKSZ))[lane];
    const float2 bv = ((const float2*)(bias + (size_t)bank * BANKSZ))[lane];

    const float s0 = fabsf(v.x) + bv.x;
    const float s1 = fabsf(v.y) + bv.y;

    // Monotone float->uint key (handles negative scores in the general case).
    const uint32_t u0 = __float_as_uint(s0);
    const uint32_t u1 = __float_as_uint(s1);
    const uint32_t k0 = (u0 & 0x80000000u) ? ~u0 : (u0 | 0x80000000u);
    const uint32_t k1 = (u1 & 0x80000000u) ? ~u1 : (u1 | 0x80000000u);

    // count of keys >= Q across the row (wave-uniform result)
    auto cnt = [&](uint32_t Q) -> int {
        return __popcll(__ballot(k0 >= Q)) + __popcll(__ballot(k1 >= Q));
    };

    // Invariant: cnt(LO) >= 16 > cnt(HI).  (cnt(0)=128; HI=0xFFFFFFFF safe for
    // any non-NaN data.)  Exit early when a probe hits exactly 16.
    uint32_t LO = 0u, HI = 0xFFFFFFFFu;

    {   // seed 1: key(1.5f)
        const uint32_t Q = 0xBFC00000u;
        const int c = cnt(Q);
        if (c >= TOPK) LO = Q; else HI = Q;
        if (c != TOPK) {
            // seed 2: key(1.58f) or key(1.44f), inside the new bracket
            const uint32_t Q2 = (c > TOPK) ? 0xBFCA3D71u : 0xBFB851ECu;
            const int c2 = cnt(Q2);
            if (c2 >= TOPK) LO = Q2; else HI = Q2;
            if (c2 != TOPK) {
                // plain binary search on the uint key space
                for (int it = 0; it < 32; ++it) {
                    const uint32_t Q3 = LO + ((HI - LO) >> 1);
                    if (Q3 == LO) break;          // bracket width 1: T = LO (ties)
                    const int c3 = cnt(Q3);
                    if (c3 >= TOPK) {
                        LO = Q3;
                        if (c3 == TOPK) break;    // exact: T = Q3 = LO
                    } else {
                        HI = Q3;
                    }
                }
            }
        }
    }
    const uint32_t T = LO;   // the 16th-largest key (or exact-count probe)

    // Reconstruct selection: all strictly-greater, then fill remaining r slots
    // from keys == T in element-index order (jax.lax.top_k tie-break).
    const unsigned long long g0 = __ballot(k0 > T);
    const unsigned long long g1 = __ballot(k1 > T);
    const unsigned long long e0 = __ballot(k0 == T);
    const unsigned long long e1 = __ballot(k1 == T);
    const int r = TOPK - (__popcll(g0) + __popcll(g1));

    const unsigned long long lt = (1ull << lane) - 1ull;
    // element index = 2*lane + slot; earlier tied elements:
    const int rank0 = __popcll(e0 & lt) + __popcll(e1 & lt);
    const int rank1 = rank0 + ((k0 == T) ? 1 : 0);

    const bool sel0 = (k0 > T) || ((k0 == T) && (rank0 < r));
    const bool sel1 = (k1 > T) || ((k1 == T) && (rank1 < r));

    float2 o;
    o.x = sel0 ? v.x : 0.0f;
    o.y = sel1 ? v.y : 0.0f;
    ((float2*)(out + (size_t)row * BANKSZ))[lane] = o;
}

extern "C" void kernel_launch(void* const* d_in, const int* in_sizes, int n_in,
                              void* d_out, int out_size, void* d_ws, size_t ws_size,
                              hipStream_t stream) {
    const float* x    = (const float*)d_in[0];
    const float* bias = (const float*)d_in[1];
    const float* nat  = (const float*)d_in[2];
    float* out = (float*)d_out;

    const int blocks = N_ROWS / 4;  // 4 rows per 256-thread block
    balanced_topk_kernel<<<dim3(blocks), dim3(256), 0, stream>>>(x, bias, nat, out);
}

// Round 3
// 441.412 us; speedup vs baseline: 1.7076x; 1.0848x over previous
//
#include <hip/hip_runtime.h>
#include <cstdint>

// x: [4,4096,4096] fp32 -> rows of 128 over [T=16384, N_BANKS=32, BANK=128]
// scores = |x| + bias[bank][:]; mask = top-16 per row (ties -> lowest index);
// out0 = x * mask; out1 = num_assigned_tokens (pass-through).
#define BANKSZ   128
#define N_BANKS  32
#define TOPK     16
#define N_TOKENS (4 * 4096)
#define N_ROWS   (N_TOKENS * N_BANKS)           // 524288
#define OUT0_SZ  (N_TOKENS * N_BANKS * BANKSZ)  // 67108864
#define NAT_SZ   4096

#define NBLK          2048
#define WAVES_TOTAL   (NBLK * 4)                 // 8192
#define ROWS_PER_WAVE (N_ROWS / WAVES_TOTAL)     // 64

// One wave per row per iteration; lane L holds elements 2L, 2L+1.
// Persistent waves: each wave loops over 64 rows (stride 8192 rows), with a
// one-row-ahead prefetch. Bank index is invariant along the stride
// (8192 % 32 == 0) so bias is loaded once per wave.
// Threshold = 16th-largest monotone key: 5 parallel seed probes at the
// |N(0,1)| 16-of-128 order-statistic quantiles, branchless s_cselect bracket
// update, then a short dependent binary search with exact-count early collapse.
// Seeding is exact for ANY data (counts are monotone in the probe).
__global__ __launch_bounds__(256) void balanced_topk_kernel(
    const float* __restrict__ x,
    const float* __restrict__ bias,
    const float* __restrict__ nat,
    float* __restrict__ out)
{
    const int lane = threadIdx.x & 63;
    const int wid  = (blockIdx.x << 2) | (threadIdx.x >> 6);   // 0..8191

    // second output: pass-through, handled by the first 16 blocks
    if (blockIdx.x < (NAT_SZ / 256)) {
        const int i = blockIdx.x * 256 + threadIdx.x;
        out[(size_t)OUT0_SZ + i] = nat[i];
    }

    // bank of every row this wave touches: (wid + i*8192) & 31 == wid & 31
    const int bank = wid & (N_BANKS - 1);
    const float2 bv = ((const float2*)(bias + (size_t)bank * BANKSZ))[lane];

    const float2* __restrict__ x2 = (const float2*)x;
    float2*       __restrict__ o2 = (float2*)out;

    uint32_t idx = (uint32_t)wid * 64u + (uint32_t)lane;  // float2 index
    const uint32_t stride = (uint32_t)WAVES_TOTAL * 64u;  // 524288 float2/iter

    float2 v = x2[idx];

    for (int i = 0; i < ROWS_PER_WAVE; ++i) {
        const float2  vc  = v;
        const uint32_t cur = idx;
        idx += stride;
        if (i != ROWS_PER_WAVE - 1) v = x2[idx];   // prefetch next row

        const float s0 = fabsf(vc.x) + bv.x;
        const float s1 = fabsf(vc.y) + bv.y;

        // monotone float->uint key (exact for negative scores too)
        const uint32_t u0 = __float_as_uint(s0);
        const uint32_t u1 = __float_as_uint(s1);
        const uint32_t k0 = u0 ^ (uint32_t)(((int32_t)u0 >> 31) | 0x80000000);
        const uint32_t k1 = u1 ^ (uint32_t)(((int32_t)u1 >> 31) | 0x80000000);

#define CNT(Q) (__popcll(__ballot(k0 >= (Q))) + __popcll(__ballot(k1 >= (Q))))

        // 5 independent seed probes: keys of floats 1.25, 1.40625, 1.53125,
        // 1.65625, 1.8125 (key = bits | 0x80000000 for positive floats)
        const int c1 = CNT(0xBFA00000u);
        const int c2 = CNT(0xBFB40000u);
        const int c3 = CNT(0xBFC40000u);
        const int c4 = CNT(0xBFD40000u);
        const int c5 = CNT(0xBFE80000u);

        // branchless bracket: LO = largest seed with cnt>=16, HI = smallest with cnt<16
        uint32_t LO = 0u, HI = 0xFFFFFFFFu;
        if (c1 >= TOPK) LO = 0xBFA00000u;
        if (c2 >= TOPK) LO = 0xBFB40000u;
        if (c3 >= TOPK) LO = 0xBFC40000u;
        if (c4 >= TOPK) LO = 0xBFD40000u;
        if (c5 >= TOPK) LO = 0xBFE80000u;
        if (c5 <  TOPK) HI = 0xBFE80000u;
        if (c4 <  TOPK) HI = 0xBFD40000u;
        if (c3 <  TOPK) HI = 0xBFC40000u;
        if (c2 <  TOPK) HI = 0xBFB40000u;
        if (c1 <  TOPK) HI = 0xBFA00000u;
        // exact-count collapse -> width-1 bracket (loop skips entirely)
        if (c1 == TOPK) { LO = 0xBFA00000u; HI = 0xBFA00001u; }
        if (c2 == TOPK) { LO = 0xBFB40000u; HI = 0xBFB40001u; }
        if (c3 == TOPK) { LO = 0xBFC40000u; HI = 0xBFC40001u; }
        if (c4 == TOPK) { LO = 0xBFD40000u; HI = 0xBFD40001u; }
        if (c5 == TOPK) { LO = 0xBFE80000u; HI = 0xBFE80001u; }

        // dependent tail: invariant cnt(LO) >= 16 > cnt(HI)
        while (HI - LO > 1u) {
            const uint32_t Q = LO + ((HI - LO) >> 1);
            const int c = CNT(Q);
            const uint32_t nHI = (c >= TOPK) ? HI : Q;
            LO = (c >= TOPK) ? Q : LO;
            HI = (c == TOPK) ? (Q + 1u) : nHI;
        }
        const uint32_t T = LO;   // the 16th-largest key
#undef CNT

        // reconstruction
        const unsigned long long g0 = __ballot(k0 >= T);
        const unsigned long long g1 = __ballot(k1 >= T);
        const int cge = __popcll(g0) + __popcll(g1);

        float2 o;
        if (cge == TOPK) {
            // no ties straddling the threshold (overwhelmingly common)
            o.x = (k0 >= T) ? vc.x : 0.0f;
            o.y = (k1 >= T) ? vc.y : 0.0f;
        } else {
            // ties at T: fill remaining r slots in element-index order
            const unsigned long long e0 = __ballot(k0 == T);
            const unsigned long long e1 = __ballot(k1 == T);
            const int r = TOPK - (cge - (__popcll(e0) + __popcll(e1)));
            const unsigned long long lt = (1ull << lane) - 1ull;
            const int rank0 = __popcll(e0 & lt) + __popcll(e1 & lt);
            const int rank1 = rank0 + ((k0 == T) ? 1 : 0);
            const bool s0 = (k0 > T) || ((k0 == T) && (rank0 < r));
            const bool s1 = (k1 > T) || ((k1 == T) && (rank1 < r));
            o.x = s0 ? vc.x : 0.0f;
            o.y = s1 ? vc.y : 0.0f;
        }
        o2[cur] = o;
    }
}

extern "C" void kernel_launch(void* const* d_in, const int* in_sizes, int n_in,
                              void* d_out, int out_size, void* d_ws, size_t ws_size,
                              hipStream_t stream) {
    const float* x    = (const float*)d_in[0];
    const float* bias = (const float*)d_in[1];
    const float* nat  = (const float*)d_in[2];
    float* out = (float*)d_out;

    balanced_topk_kernel<<<dim3(NBLK), dim3(256), 0, stream>>>(x, bias, nat, out);
}